// Round 14
// baseline (10113.517 us; speedup 1.0000x reference)
//
#include <hip/hip_runtime.h>

typedef __attribute__((ext_vector_type(8))) short short8;
typedef __attribute__((ext_vector_type(4))) float f32x4;

#define MFMA_B16(a, b, c) __builtin_amdgcn_mfma_f32_16x16x32_bf16((a), (b), (c), 0, 0, 0)

#define TSTEPS 256
#define NBATCH 64
#define HID    512
#define NBLK   32
#define UB     16
#define HSLOT  (NBATCH * HID)

__device__ __forceinline__ unsigned short f2bf(float f) {
  unsigned int u = __float_as_uint(f);
  u += 0x7fffu + ((u >> 16) & 1u);
  return (unsigned short)(u >> 16);
}
__device__ __forceinline__ float bf2f(unsigned short s) {
  return __uint_as_float(((unsigned int)s) << 16);
}
__device__ __forceinline__ float sigm(float x) { return 1.0f / (1.0f + __expf(-x)); }
__device__ __forceinline__ float tanhf_(float x) {
  float xc = fminf(fmaxf(x, -15.0f), 15.0f);
  float e = __expf(2.0f * xc);
  return (e - 1.0f) / (e + 1.0f);
}

__device__ __forceinline__ unsigned int ld_flag(const unsigned int* p) {
  return __hip_atomic_load(p, __ATOMIC_RELAXED, __HIP_MEMORY_SCOPE_AGENT);
}
__device__ __forceinline__ void st_flag(unsigned int* p, unsigned int v) {
  __hip_atomic_store(p, v, __ATOMIC_RELAXED, __HIP_MEMORY_SCOPE_AGENT);
}
__device__ __forceinline__ void st_u64(unsigned long long* p, unsigned long long v) {
  __hip_atomic_store(p, v, __ATOMIC_RELAXED, __HIP_MEMORY_SCOPE_AGENT);
}
__device__ __forceinline__ short8 ld_llc16(const unsigned short* p) {
  union { unsigned long long q[2]; short8 s; } u;
  unsigned long long* a = (unsigned long long*)p;
  u.q[0] = __hip_atomic_load(a,     __ATOMIC_RELAXED, __HIP_MEMORY_SCOPE_AGENT);
  u.q[1] = __hip_atomic_load(a + 1, __ATOMIC_RELAXED, __HIP_MEMORY_SCOPE_AGENT);
  return u.s;
}

// All fp32->bf16 conversions in one launch; dst = contiguous region at xbf.
__global__ void cvt_all(const float* __restrict__ x,
                        const float* __restrict__ fWih0, const float* __restrict__ bWih0,
                        const float* __restrict__ fWihR, const float* __restrict__ bWihR,
                        const float* __restrict__ fWhh,  const float* __restrict__ bWhh,
                        const float* __restrict__ projW,
                        unsigned short* __restrict__ dst)
{
  const int tot = 6815744;
  for (int i = blockIdx.x * blockDim.x + threadIdx.x; i < tot; i += gridDim.x * blockDim.x) {
    const float* src; int r;
    if      (i < 2097152) { src = x;                 r = i; }
    else if (i < 2359296) { src = fWih0;             r = i - 2097152; }
    else if (i < 2621440) { src = bWih0;             r = i - 2359296; }
    else if (i < 3145728) { src = fWihR;             r = i - 2621440; }
    else if (i < 3670016) { src = bWihR;             r = i - 3145728; }
    else if (i < 4194304) { src = fWihR + 2097152;   r = i - 3670016; }
    else if (i < 4718592) { src = bWihR + 2097152;   r = i - 4194304; }
    else if (i < 5505024) { src = fWhh;              r = i - 4718592; }
    else if (i < 6291456) { src = bWhh;              r = i - 5505024; }
    else                  { src = projW;             r = i - 6291456; }
    f32x4 v = ((const f32x4*)src)[r];
    union { unsigned short u[4]; unsigned long long q; } o;
    o.u[0] = f2bf(v[0]); o.u[1] = f2bf(v[1]); o.u[2] = f2bf(v[2]); o.u[3] = f2bf(v[3]);
    ((unsigned long long*)dst)[i] = o.q;
  }
}

// gates_x precompute (R13-proven): operand-swapped MFMA, packed 8B stores.
// Grid: (128 t-pairs, 16 row-blocks), t-pair fastest (weight slice L2-hot).
template<int K>
__global__ __launch_bounds__(256)
void gates_gemm(const unsigned short* __restrict__ act,
                const unsigned short* __restrict__ wcat,
                const float* __restrict__ bias_f,
                const float* __restrict__ bias_b,
                unsigned short* __restrict__ gates)
{
  const int lane = threadIdx.x & 63;
  const int wave = threadIdx.x >> 6;
  const int n = lane & 15, kb = lane >> 4;
  const int t0 = blockIdx.x * 2;
  const int rbase = blockIdx.y * 256 + wave * 64;

  f32x4 acc[2][4][4];   // [t2][mt: r-tile][nt: batch-tile]
  #pragma unroll
  for (int mt = 0; mt < 4; ++mt) {
    int r = rbase + mt * 16 + n;
    float bv = (r < 2048) ? bias_f[r] : bias_b[r - 2048];
    f32x4 bi = (f32x4){bv, bv, bv, bv};
    #pragma unroll
    for (int nt = 0; nt < 4; ++nt) { acc[0][mt][nt] = bi; acc[1][mt][nt] = bi; }
  }
  const unsigned short* wrow  = wcat + (size_t)(rbase + n) * K + kb * 8;
  const unsigned short* arow0 = act + ((size_t)t0 * 64 + n) * K + kb * 8;
  const unsigned short* arow1 = arow0 + (size_t)64 * K;
  #pragma unroll 2
  for (int ks = 0; ks < K / 32; ++ks) {
    short8 wf[4], b0[4], b1[4];
    #pragma unroll
    for (int mt = 0; mt < 4; ++mt) wf[mt] = *(const short8*)(wrow + (size_t)mt * 16 * K + ks * 32);
    #pragma unroll
    for (int nt = 0; nt < 4; ++nt) {
      b0[nt] = *(const short8*)(arow0 + (size_t)nt * 16 * K + ks * 32);
      b1[nt] = *(const short8*)(arow1 + (size_t)nt * 16 * K + ks * 32);
    }
    #pragma unroll
    for (int mt = 0; mt < 4; ++mt)
      #pragma unroll
      for (int nt = 0; nt < 4; ++nt) {
        acc[0][mt][nt] = MFMA_B16(b0[nt], wf[mt], acc[0][mt][nt]);  // A=act, B=W
        acc[1][mt][nt] = MFMA_B16(b1[nt], wf[mt], acc[1][mt][nt]);
      }
  }
  #pragma unroll
  for (int t2 = 0; t2 < 2; ++t2) {
    unsigned short* gbase = gates + (size_t)(t0 + t2) * 4096 * 64;
    #pragma unroll
    for (int mt = 0; mt < 4; ++mt) {
      const size_t roff = (size_t)(rbase + mt * 16 + n) * 64;
      #pragma unroll
      for (int nt = 0; nt < 4; ++nt) {
        union { unsigned short us[4]; unsigned long long q; } o;
        #pragma unroll
        for (int i = 0; i < 4; ++i) o.us[i] = f2bf(acc[t2][mt][nt][i]);
        *(unsigned long long*)(gbase + roff + nt * 16 + kb * 4) = o.q;
      }
    }
  }
}

// Persistent bidirectional LSTM layer scan — 16 blocks/dir, 32 units/block,
// with the R10-PROVEN protocol (8B agent-atomic loads/stores, vmcnt, replicated
// flags, wave role split). Clean isolation of R11's tiling from its bad loads:
// halves LLC read transactions (16 blocks/dir reading 64KB each vs 32) and
// halves barrier arrivals.
// h layout: [k-slice ks = producer jb][batch][32 units]  (jb*2048 + b*32 + u)
__global__ __launch_bounds__(256, 1)
void scan2_kernel(const unsigned short* __restrict__ gates,
                  unsigned short* __restrict__ act_out,
                  const unsigned short* __restrict__ whh_f,
                  const unsigned short* __restrict__ whh_b,
                  const float* __restrict__ init_f,
                  const float* __restrict__ init_b,
                  const float* __restrict__ masks,
                  unsigned short* hb,          // [2 dirs][2 slots][HSLOT] bf16
                  unsigned int* bar,           // per layer: 32 lines x 32 uints
                  float* out_h, float* out_c)
{
  const int bid  = blockIdx.x;
  const int dir  = bid >> 4;
  const int jb   = bid & 15;
  const int j0   = jb * 32;
  const int lane = threadIdx.x & 63;
  const int wave = threadIdx.x >> 6;
  const int n    = lane & 15;
  const int kb   = lane >> 4;
  const int u    = n & 7;
  const bool hif = (n >= 8);

  const unsigned short* whh = dir ? whh_b : whh_f;
  const float* init = dir ? init_b : init_f;
  const unsigned int* mypoll = bar + ((dir * 16 + jb) << 5) + (lane & 15);
  unsigned int* scat = bar + ((dir * 16 + (lane & 15)) << 5) + jb;  // lane<16
  unsigned short* hbd = hb + dir * (2 * HSLOT);
  float* oh = out_h + dir * (NBATCH * HID);
  float* oc = out_c + dir * (NBATCH * HID);

  // 8 n-tiles: q=0..3 -> [i|f] units (q*8..q*8+8); q=4..7 -> [g|o] same
  int wr[8];
  #pragma unroll
  for (int q = 0; q < 4; ++q) {
    int unit = j0 + q * 8 + u;
    wr[q]     = hif ? (512 + unit) : unit;
    wr[4 + q] = wr[q] + 1024;
  }

  __shared__ short8 wlds[16 * 8 * 64];                // 128 KB
  __shared__ unsigned short lsm[2][NBATCH * 32];      // 2x4 KB

  for (int g = threadIdx.x; g < 8192; g += 256) {
    int n_ = g & 15, kb_ = (g >> 4) & 3, q_ = (g >> 6) & 7, ks_ = g >> 9;
    int unit = j0 + (q_ & 3) * 8 + (n_ & 7);
    int grow = ((n_ >= 8) ? 512 : 0) + unit + (q_ >> 2) * 1024;
    wlds[g] = *(const short8*)(whh + (size_t)grow * HID + ks_ * 32 + kb_ * 8);
  }

  float cs[4][4];
  #pragma unroll
  for (int uh = 0; uh < 4; ++uh)
    #pragma unroll
    for (int i = 0; i < 4; ++i)
      cs[uh][i] = init[512 + j0 + uh * 8 + u];

  __syncthreads();

  // h0 init (lane = batch), proven 8B agent stores
  if (wave == 0) {
    union { unsigned short us[32]; unsigned long long q[8]; } iv;
    #pragma unroll
    for (int k = 0; k < 32; ++k) iv.us[k] = f2bf(init[j0 + k]);
    unsigned long long* hd = (unsigned long long*)(hbd + jb * 2048 + lane * 32);
    #pragma unroll
    for (int k = 0; k < 8; ++k) st_u64(hd + k, iv.q[k]);
    asm volatile("s_waitcnt vmcnt(0)" ::: "memory");
    if (lane < 16) st_flag(scat, 1u);
  }

  f32x4 acc_e[8], acc_o[8];

  for (int t = 0; t < TSTEPS; ++t) {
    const int tt = dir ? (TSTEPS - 1 - t) : t;

    // prefetch: mask + gate pre-activations before the poll
    f32x4 mk = *(const f32x4*)(masks + tt * NBATCH + wave * 16 + kb * 4);
    {
      const unsigned short* gb = gates + ((size_t)tt * 4096 + dir * 2048) * 64 + wave * 16 + kb * 4;
      #pragma unroll
      for (int q = 0; q < 8; ++q) {
        union { unsigned long long q8; unsigned short us[4]; } gv;
        gv.q8 = *(const unsigned long long*)(gb + (size_t)wr[q] * 64);
        acc_e[q] = (f32x4){bf2f(gv.us[0]), bf2f(gv.us[1]), bf2f(gv.us[2]), bf2f(gv.us[3])};
        acc_o[q] = (f32x4){0.f, 0.f, 0.f, 0.f};
      }
    }

    // wait for h(t-1): poll this block's private flag line (16 producers)
    {
      const unsigned int tgt = t + 1;
      while (!__all((int)(ld_flag(mypoll) >= tgt)))
        __builtin_amdgcn_s_sleep(1);
    }

    // h(t-1) @ Whh_slice: proven 8B agent loads from coherent point
    {
      const unsigned short* hrow = hbd + (t & 1) * HSLOT + (wave * 16 + n) * 32 + kb * 8;
      short8 hf[16];
      #pragma unroll
      for (int ks = 0; ks < 16; ++ks) hf[ks] = ld_llc16(hrow + ks * 2048);
      #pragma unroll
      for (int ks = 0; ks < 16; ++ks) {
        f32x4* ac = (ks & 1) ? acc_o : acc_e;
        #pragma unroll
        for (int q = 0; q < 8; ++q)
          ac[q] = MFMA_B16(hf[ks], wlds[(ks * 8 + q) * 64 + lane], ac[q]);
      }
    }

    #pragma unroll
    for (int uh = 0; uh < 4; ++uh) {
      f32x4 aif = acc_e[uh] + acc_o[uh];
      f32x4 ago = acc_e[4 + uh] + acc_o[4 + uh];
      f32x4 oif, ogo;
      #pragma unroll
      for (int r = 0; r < 4; ++r) {
        oif[r] = __shfl_xor(aif[r], 8, 64);
        ogo[r] = __shfl_xor(ago[r], 8, 64);
      }
      #pragma unroll
      for (int i = 0; i < 4; ++i) {
        float vi = hif ? oif[i] : aif[i];
        float vf = hif ? aif[i] : oif[i];
        float vg = hif ? ogo[i] : ago[i];
        float vo = hif ? ago[i] : ogo[i];
        float cn = (sigm(vf) * cs[uh][i] + sigm(vi) * tanhf_(vg)) * mk[i];
        float hvv = sigm(vo) * tanhf_(cn) * mk[i];
        cs[uh][i] = cn;
        if (!hif) {
          const int b = wave * 16 + kb * 4 + i;
          lsm[t & 1][b * 32 + uh * 8 + u] = f2bf(hvv);
          if (t == TSTEPS - 1) {
            oh[b * HID + j0 + uh * 8 + u] = hvv;
            oc[b * HID + j0 + uh * 8 + u] = cn;
          }
        }
      }
    }

    __syncthreads();  // lsm[t&1] writes -> wave0/wave1 reads

    if (wave == 0) {
      // critical path: h publish (8B agent stores) + flag scatter
      if (t + 1 < TSTEPS) {
        const unsigned long long* lq = (const unsigned long long*)lsm[t & 1] + lane * 8;
        unsigned long long* hd = (unsigned long long*)
            (hbd + ((t + 1) & 1) * HSLOT + jb * 2048 + lane * 32);
        #pragma unroll
        for (int k = 0; k < 8; ++k) st_u64(hd + k, lq[k]);
        asm volatile("s_waitcnt vmcnt(0)" ::: "memory");
        if (lane < 16) st_flag(scat, (unsigned int)(t + 2));
      }
    } else if (wave == 1) {
      // act_out store, off the critical path
      const short8* ls = (const short8*)lsm[t & 1] + lane * 4;
      short8* ar = (short8*)(act_out + ((size_t)tt * NBATCH + lane) * (2 * HID) + dir * HID + j0);
      ar[0] = ls[0]; ar[1] = ls[1]; ar[2] = ls[2]; ar[3] = ls[3];
    }
  }
}

// ---------------- fallback (no gates precompute), R8/R13-proven ------------
template<int DIN>
__global__ __launch_bounds__(256, 1)
void scan_kernel(const unsigned short* __restrict__ act_in,
                 unsigned short* __restrict__ act_out,
                 const unsigned short* __restrict__ wih_f,
                 const unsigned short* __restrict__ wih_b,
                 const unsigned short* __restrict__ whh_f,
                 const unsigned short* __restrict__ whh_b,
                 const float* __restrict__ bias_f,
                 const float* __restrict__ bias_b,
                 const float* __restrict__ init_f,
                 const float* __restrict__ init_b,
                 const float* __restrict__ masks,
                 unsigned short* hb, unsigned int* bar,
                 float* out_h, float* out_c)
{
  const int bid = blockIdx.x;
  const int dir = bid >> 5;
  const int jb = bid & (NBLK - 1);
  const int j0 = jb * UB;
  const int lane = threadIdx.x & 63;
  const int wave = threadIdx.x >> 6;
  const int n = lane & 15, kb = lane >> 4, u = n & 7;
  const bool hif = (n >= 8);

  const unsigned short* wih = dir ? wih_b : wih_f;
  const unsigned short* whh = dir ? whh_b : whh_f;
  const float* bias = dir ? bias_b : bias_f;
  const float* init = dir ? init_b : init_f;
  const unsigned int* mypoll = bar + ((dir * 32 + jb) << 5) + (lane & 31);
  unsigned int* scat = bar + ((dir * 32 + (lane & 31)) << 5) + jb;
  unsigned short* hbd = hb + dir * (2 * HSLOT);
  float* oh = out_h + dir * (NBATCH * HID);
  float* oc = out_c + dir * (NBATCH * HID);

  int wr[4];
  wr[0] = hif ? (512 + j0 + u) : (j0 + u);
  wr[1] = wr[0] + 8; wr[2] = wr[0] + 1024; wr[3] = wr[0] + 1032;
  float bb[4];
  const unsigned short* wihp[4];
  #pragma unroll
  for (int q = 0; q < 4; ++q) {
    bb[q] = bias[wr[q]];
    wihp[q] = wih + (size_t)wr[q] * DIN + kb * 8;
  }
  __shared__ short8 wlds[16 * 4 * 64];
  __shared__ unsigned short lsm[NBATCH * UB];
  for (int g = threadIdx.x; g < 4096; g += 256) {
    int n_ = g & 15, kb_ = (g >> 4) & 3, q_ = (g >> 6) & 3, ks_ = g >> 8;
    int grow = ((n_ >= 8) ? 512 : 0) + j0 + (n_ & 7) + (q_ & 1) * 8 + (q_ >> 1) * 1024;
    wlds[g] = *(const short8*)(whh + (size_t)grow * HID + ks_ * 32 + kb_ * 8);
  }
  float cs[2][4];
  #pragma unroll
  for (int uh = 0; uh < 2; ++uh)
    #pragma unroll
    for (int i = 0; i < 4; ++i) cs[uh][i] = init[512 + j0 + uh * 8 + u];
  __syncthreads();
  if (wave == 0) {
    union { unsigned short us[16]; unsigned long long q[4]; } iv;
    #pragma unroll
    for (int k = 0; k < 16; ++k) iv.us[k] = f2bf(init[j0 + k]);
    unsigned long long* hd = (unsigned long long*)(hbd + jb * (NBATCH * UB) + lane * UB);
    #pragma unroll
    for (int k = 0; k < 4; ++k) st_u64(hd + k, iv.q[k]);
    asm volatile("s_waitcnt vmcnt(0)" ::: "memory");
    if (lane < 32) st_flag(scat, 1u);
  }
  f32x4 acc_e[4], acc_o[4];
  auto wih_load = [&](int tstep) {
    #pragma unroll
    for (int q = 0; q < 4; ++q) {
      acc_e[q] = (f32x4){bb[q], bb[q], bb[q], bb[q]};
      acc_o[q] = (f32x4){0.f, 0.f, 0.f, 0.f};
    }
    const int tt2 = dir ? (TSTEPS - 1 - tstep) : tstep;
    const unsigned short* arow = act_in + ((size_t)tt2 * NBATCH + wave * 16 + n) * DIN + kb * 8;
    #pragma unroll
    for (int kt = 0; kt < DIN / 32; kt += 2) {
      short8 a0 = *(const short8*)(arow + kt * 32);
      short8 a1 = *(const short8*)(arow + kt * 32 + 32);
      #pragma unroll
      for (int q = 0; q < 4; ++q) {
        acc_e[q] = MFMA_B16(a0, *(const short8*)(wihp[q] + kt * 32), acc_e[q]);
        acc_o[q] = MFMA_B16(a1, *(const short8*)(wihp[q] + kt * 32 + 32), acc_o[q]);
      }
    }
  };
  wih_load(0);
  for (int t = 0; t < TSTEPS; ++t) {
    const int tt = dir ? (TSTEPS - 1 - t) : t;
    f32x4 mk = *(const f32x4*)(masks + tt * NBATCH + wave * 16 + kb * 4);
    {
      const unsigned int tgt = t + 1;
      while (!__all((int)(ld_flag(mypoll) >= tgt))) __builtin_amdgcn_s_sleep(1);
    }
    {
      const unsigned short* hrow = hbd + (t & 1) * HSLOT
                                 + (kb >> 1) * 1024 + (kb & 1) * 8 + (wave * 16 + n) * UB;
      short8 hf[16];
      #pragma unroll
      for (int ks = 0; ks < 16; ++ks) hf[ks] = ld_llc16(hrow + ks * 2048);
      #pragma unroll
      for (int ks = 0; ks < 16; ++ks) {
        f32x4* ac = (ks & 1) ? acc_o : acc_e;
        #pragma unroll
        for (int q = 0; q < 4; ++q)
          ac[q] = MFMA_B16(hf[ks], wlds[(ks * 4 + q) * 64 + lane], ac[q]);
      }
    }
    #pragma unroll
    for (int uh = 0; uh < 2; ++uh) {
      f32x4 aif = acc_e[uh] + acc_o[uh];
      f32x4 ago = acc_e[2 + uh] + acc_o[2 + uh];
      f32x4 oif, ogo;
      #pragma unroll
      for (int r = 0; r < 4; ++r) {
        oif[r] = __shfl_xor(aif[r], 8, 64);
        ogo[r] = __shfl_xor(ago[r], 8, 64);
      }
      #pragma unroll
      for (int i = 0; i < 4; ++i) {
        float vi = hif ? oif[i] : aif[i];
        float vf = hif ? aif[i] : oif[i];
        float vg = hif ? ogo[i] : ago[i];
        float vo = hif ? ago[i] : ogo[i];
        float cn = (sigm(vf) * cs[uh][i] + sigm(vi) * tanhf_(vg)) * mk[i];
        float hvv = sigm(vo) * tanhf_(cn) * mk[i];
        cs[uh][i] = cn;
        if (!hif) {
          const int b = wave * 16 + kb * 4 + i;
          lsm[b * UB + uh * 8 + u] = f2bf(hvv);
          if (t == TSTEPS - 1) {
            oh[b * HID + j0 + uh * 8 + u] = hvv;
            oc[b * HID + j0 + uh * 8 + u] = cn;
          }
        }
      }
    }
    __syncthreads();
    if (wave == 0) {
      const unsigned long long* lq = (const unsigned long long*)lsm;
      unsigned long long q0 = lq[lane * 4 + 0], q1 = lq[lane * 4 + 1];
      unsigned long long q2 = lq[lane * 4 + 2], q3 = lq[lane * 4 + 3];
      if (t + 1 < TSTEPS) {
        unsigned long long* hd = (unsigned long long*)
            (hbd + ((t + 1) & 1) * HSLOT + jb * (NBATCH * UB) + lane * UB);
        st_u64(hd + 0, q0); st_u64(hd + 1, q1);
        st_u64(hd + 2, q2); st_u64(hd + 3, q3);
        asm volatile("s_waitcnt vmcnt(0)" ::: "memory");
        if (lane < 32) st_flag(scat, (unsigned int)(t + 2));
      }
      union { unsigned long long q[2]; short8 s; } p0, p1;
      p0.q[0] = q0; p0.q[1] = q1; p1.q[0] = q2; p1.q[1] = q3;
      short8* ar = (short8*)(act_out + ((size_t)tt * NBATCH + lane) * (2 * HID) + dir * HID + j0);
      ar[0] = p0.s; ar[1] = p1.s;
    }
    if (t + 1 < TSTEPS) wih_load(t + 1);
  }
}

// Highway gate: g = sigmoid(raw @ projW^T + projb); out = g*raw + (1-g)*inp
template<int FINAL>
__global__ __launch_bounds__(256)
void highway_kernel(const unsigned short* __restrict__ raw,
                    unsigned short* __restrict__ inp,
                    const unsigned short* __restrict__ pw,
                    const float* __restrict__ pb,
                    float* __restrict__ outf)
{
  const int lane = threadIdx.x & 63;
  const int wave = threadIdx.x >> 6;
  const int n = lane & 15, kb = lane >> 4;
  const int r0 = blockIdx.x * 64 + wave * 16;
  const int c0 = blockIdx.y * 64;
  f32x4 acc[4];
  #pragma unroll
  for (int nt = 0; nt < 4; ++nt) {
    float b = pb[c0 + nt * 16 + n];
    acc[nt] = (f32x4){b, b, b, b};
  }
  const unsigned short* arow = raw + (r0 + n) * 1024 + kb * 8;
  #pragma unroll 4
  for (int kt = 0; kt < 32; ++kt) {
    short8 a = *(const short8*)(arow + kt * 32);
    #pragma unroll
    for (int nt = 0; nt < 4; ++nt) {
      short8 b = *(const short8*)(pw + (c0 + nt * 16 + n) * 1024 + kt * 32 + kb * 8);
      acc[nt] = MFMA_B16(a, b, acc[nt]);
    }
  }
  #pragma unroll
  for (int nt = 0; nt < 4; ++nt)
    #pragma unroll
    for (int i = 0; i < 4; ++i) {
      int row = r0 + kb * 4 + i;
      int col = c0 + nt * 16 + n;
      float g = sigm(acc[nt][i]);
      float rv = bf2f(raw[row * 1024 + col]);
      float iv = bf2f(inp[row * 1024 + col]);
      float ov = g * rv + (1.0f - g) * iv;
      if (FINAL) outf[row * 1024 + col] = ov;
      else       inp[row * 1024 + col] = f2bf(ov);
    }
}

extern "C" void kernel_launch(void* const* d_in, const int* in_sizes, int n_in,
                              void* d_out, int out_size, void* d_ws, size_t ws_size,
                              hipStream_t stream) {
  const float* x     = (const float*)d_in[0];
  const float* masks = (const float*)d_in[1];
  const float* fWih0 = (const float*)d_in[2];
  const float* fWihR = (const float*)d_in[3];
  const float* fWhh  = (const float*)d_in[4];
  const float* fb    = (const float*)d_in[5];
  const float* bWih0 = (const float*)d_in[6];
  const float* bWihR = (const float*)d_in[7];
  const float* bWhh  = (const float*)d_in[8];
  const float* bbias = (const float*)d_in[9];
  const float* fInit = (const float*)d_in[10];
  const float* bInit = (const float*)d_in[11];
  const float* projW = (const float*)d_in[12];
  const float* projB = (const float*)d_in[13];
  float* out = (float*)d_out;

  char* ws = (char*)d_ws;
  unsigned short* bufA  = (unsigned short*)(ws + 0);           // 33,554,432
  unsigned short* bufB  = (unsigned short*)(ws + 33554432);    // 33,554,432
  unsigned short* xbf   = (unsigned short*)(ws + 67108864);    // 16,777,216
  unsigned short* wcat0 = (unsigned short*)(ws + 83886080);    //  4,194,304
  unsigned short* wcat1 = (unsigned short*)(ws + 88080384);    //  8,388,608
  unsigned short* wcat2 = (unsigned short*)(ws + 96468992);    //  8,388,608
  unsigned short* whf   = (unsigned short*)(ws + 104857600);   //  6,291,456
  unsigned short* whb   = (unsigned short*)(ws + 111149056);   //  6,291,456
  unsigned short* pj    = (unsigned short*)(ws + 117440512);   //  4,194,304
  unsigned short* hbuf  = (unsigned short*)(ws + 121634816);   //    262,144
  unsigned int*   bar   = (unsigned int*)(ws + 121896960);     //     24,576
  unsigned short* gates = (unsigned short*)(ws + 121921536);   // 134,217,728
  const bool gx = ws_size >= 256139264ull;

  hipMemsetAsync(bar, 0, 24576, stream);
  cvt_all<<<1024, 256, 0, stream>>>(x, fWih0, bWih0, fWihR, bWihR, fWhh, bWhh, projW, xbf);

  float* outH = out + 16777216;
  float* outC = out + 16777216 + 6*64*512;

  if (gx) {
    // layer 0
    gates_gemm<512><<<dim3(128, 16), 256, 0, stream>>>(xbf, wcat0, fb, bbias, gates);
    scan2_kernel<<<32, 256, 0, stream>>>(
        gates, bufA, whf, whb, fInit, bInit, masks, hbuf, bar, outH, outC);
    // layer 1
    gates_gemm<1024><<<dim3(128, 16), 256, 0, stream>>>(bufA, wcat1, fb + 2048, bbias + 2048, gates);
    scan2_kernel<<<32, 256, 0, stream>>>(
        gates, bufB, whf + 2048*512, whb + 2048*512, fInit + 1024, bInit + 1024,
        masks, hbuf, bar + 2048, outH + 2*64*512, outC + 2*64*512);
    highway_kernel<0><<<dim3(256, 16), 256, 0, stream>>>(bufB, bufA, pj, projB, nullptr);
    // layer 2
    gates_gemm<1024><<<dim3(128, 16), 256, 0, stream>>>(bufA, wcat2, fb + 4096, bbias + 4096, gates);
    scan2_kernel<<<32, 256, 0, stream>>>(
        gates, bufB, whf + 2*2048*512, whb + 2*2048*512, fInit + 2048, bInit + 2048,
        masks, hbuf, bar + 4096, outH + 4*64*512, outC + 4*64*512);
    highway_kernel<1><<<dim3(256, 16), 256, 0, stream>>>(bufB, bufA, pj + 1024*1024, projB + 1024, out);
  } else {
    scan_kernel<512><<<64, 256, 0, stream>>>(
        xbf, bufA, wcat0, wcat0 + 2048*512, whf, whb,
        fb, bbias, fInit, bInit, masks, hbuf, bar, outH, outC);
    scan_kernel<1024><<<64, 256, 0, stream>>>(
        bufA, bufB, wcat1, wcat1 + 2048*1024, whf + 2048*512, whb + 2048*512,
        fb + 2048, bbias + 2048, fInit + 1024, bInit + 1024, masks, hbuf, bar + 2048,
        outH + 2*64*512, outC + 2*64*512);
    highway_kernel<0><<<dim3(256, 16), 256, 0, stream>>>(bufB, bufA, pj, projB, nullptr);
    scan_kernel<1024><<<64, 256, 0, stream>>>(
        bufA, bufB, wcat2, wcat2 + 2048*1024, whf + 2*2048*512, whb + 2*2048*512,
        fb + 4096, bbias + 4096, fInit + 2048, bInit + 2048, masks, hbuf, bar + 4096,
        outH + 4*64*512, outC + 4*64*512);
    highway_kernel<1><<<dim3(256, 16), 256, 0, stream>>>(bufB, bufA, pj + 1024*1024, projB + 1024, out);
  }
}

// Round 15
// 5806.395 us; speedup vs baseline: 1.7418x; 1.7418x over previous
//
#include <hip/hip_runtime.h>

typedef __attribute__((ext_vector_type(8))) short short8;
typedef __attribute__((ext_vector_type(4))) float f32x4;

#define MFMA_B16(a, b, c) __builtin_amdgcn_mfma_f32_16x16x32_bf16((a), (b), (c), 0, 0, 0)

#define TSTEPS 256
#define NBATCH 64
#define HID    512
#define NBLK   32
#define UB     16
#define HSLOT  (NBATCH * HID)

__device__ __forceinline__ unsigned short f2bf(float f) {
  unsigned int u = __float_as_uint(f);
  u += 0x7fffu + ((u >> 16) & 1u);
  return (unsigned short)(u >> 16);
}
__device__ __forceinline__ float bf2f(unsigned short s) {
  return __uint_as_float(((unsigned int)s) << 16);
}
__device__ __forceinline__ float sigm(float x) { return 1.0f / (1.0f + __expf(-x)); }
__device__ __forceinline__ float tanhf_(float x) {
  float xc = fminf(fmaxf(x, -15.0f), 15.0f);
  float e = __expf(2.0f * xc);
  return (e - 1.0f) / (e + 1.0f);
}

__device__ __forceinline__ unsigned int ld_flag(const unsigned int* p) {
  return __hip_atomic_load(p, __ATOMIC_RELAXED, __HIP_MEMORY_SCOPE_AGENT);
}
__device__ __forceinline__ void st_flag(unsigned int* p, unsigned int v) {
  __hip_atomic_store(p, v, __ATOMIC_RELAXED, __HIP_MEMORY_SCOPE_AGENT);
}
__device__ __forceinline__ void st_u64(unsigned long long* p, unsigned long long v) {
  __hip_atomic_store(p, v, __ATOMIC_RELAXED, __HIP_MEMORY_SCOPE_AGENT);
}
__device__ __forceinline__ short8 ld_llc16(const unsigned short* p) {
  union { unsigned long long q[2]; short8 s; } u;
  unsigned long long* a = (unsigned long long*)p;
  u.q[0] = __hip_atomic_load(a,     __ATOMIC_RELAXED, __HIP_MEMORY_SCOPE_AGENT);
  u.q[1] = __hip_atomic_load(a + 1, __ATOMIC_RELAXED, __HIP_MEMORY_SCOPE_AGENT);
  return u.s;
}

// All fp32->bf16 conversions in one launch; dst = contiguous region at xbf.
__global__ void cvt_all(const float* __restrict__ x,
                        const float* __restrict__ fWih0, const float* __restrict__ bWih0,
                        const float* __restrict__ fWihR, const float* __restrict__ bWihR,
                        const float* __restrict__ fWhh,  const float* __restrict__ bWhh,
                        const float* __restrict__ projW,
                        unsigned short* __restrict__ dst)
{
  const int tot = 6815744;
  for (int i = blockIdx.x * blockDim.x + threadIdx.x; i < tot; i += gridDim.x * blockDim.x) {
    const float* src; int r;
    if      (i < 2097152) { src = x;                 r = i; }
    else if (i < 2359296) { src = fWih0;             r = i - 2097152; }
    else if (i < 2621440) { src = bWih0;             r = i - 2359296; }
    else if (i < 3145728) { src = fWihR;             r = i - 2621440; }
    else if (i < 3670016) { src = bWihR;             r = i - 3145728; }
    else if (i < 4194304) { src = fWihR + 2097152;   r = i - 3670016; }
    else if (i < 4718592) { src = bWihR + 2097152;   r = i - 4194304; }
    else if (i < 5505024) { src = fWhh;              r = i - 4718592; }
    else if (i < 6291456) { src = bWhh;              r = i - 5505024; }
    else                  { src = projW;             r = i - 6291456; }
    f32x4 v = ((const f32x4*)src)[r];
    union { unsigned short u[4]; unsigned long long q; } o;
    o.u[0] = f2bf(v[0]); o.u[1] = f2bf(v[1]); o.u[2] = f2bf(v[2]); o.u[3] = f2bf(v[3]);
    ((unsigned long long*)dst)[i] = o.q;
  }
}

// gates_x precompute: operand-swapped MFMA (A=act, B=W) so each lane's 4 acc
// elements are 4 consecutive batch addresses of one gate row -> packed 8B
// stores. Grid: (128 t-pairs, 16 row-blocks), t-pair fastest (weights L2-hot).
template<int K>
__global__ __launch_bounds__(256)
void gates_gemm(const unsigned short* __restrict__ act,
                const unsigned short* __restrict__ wcat,
                const float* __restrict__ bias_f,
                const float* __restrict__ bias_b,
                unsigned short* __restrict__ gates)
{
  const int lane = threadIdx.x & 63;
  const int wave = threadIdx.x >> 6;
  const int n = lane & 15, kb = lane >> 4;
  const int t0 = blockIdx.x * 2;
  const int rbase = blockIdx.y * 256 + wave * 64;

  f32x4 acc[2][4][4];   // [t2][mt: r-tile][nt: batch-tile]
  #pragma unroll
  for (int mt = 0; mt < 4; ++mt) {
    int r = rbase + mt * 16 + n;
    float bv = (r < 2048) ? bias_f[r] : bias_b[r - 2048];
    f32x4 bi = (f32x4){bv, bv, bv, bv};
    #pragma unroll
    for (int nt = 0; nt < 4; ++nt) { acc[0][mt][nt] = bi; acc[1][mt][nt] = bi; }
  }
  const unsigned short* wrow  = wcat + (size_t)(rbase + n) * K + kb * 8;
  const unsigned short* arow0 = act + ((size_t)t0 * 64 + n) * K + kb * 8;
  const unsigned short* arow1 = arow0 + (size_t)64 * K;
  #pragma unroll 2
  for (int ks = 0; ks < K / 32; ++ks) {
    short8 wf[4], b0[4], b1[4];
    #pragma unroll
    for (int mt = 0; mt < 4; ++mt) wf[mt] = *(const short8*)(wrow + (size_t)mt * 16 * K + ks * 32);
    #pragma unroll
    for (int nt = 0; nt < 4; ++nt) {
      b0[nt] = *(const short8*)(arow0 + (size_t)nt * 16 * K + ks * 32);
      b1[nt] = *(const short8*)(arow1 + (size_t)nt * 16 * K + ks * 32);
    }
    #pragma unroll
    for (int mt = 0; mt < 4; ++mt)
      #pragma unroll
      for (int nt = 0; nt < 4; ++nt) {
        acc[0][mt][nt] = MFMA_B16(b0[nt], wf[mt], acc[0][mt][nt]);  // A=act, B=W
        acc[1][mt][nt] = MFMA_B16(b1[nt], wf[mt], acc[1][mt][nt]);
      }
  }
  // D[row=batch part][col=r part]: r = rbase+mt*16+n; b = nt*16+kb*4+i
  #pragma unroll
  for (int t2 = 0; t2 < 2; ++t2) {
    unsigned short* gbase = gates + (size_t)(t0 + t2) * 4096 * 64;
    #pragma unroll
    for (int mt = 0; mt < 4; ++mt) {
      const size_t roff = (size_t)(rbase + mt * 16 + n) * 64;
      #pragma unroll
      for (int nt = 0; nt < 4; ++nt) {
        union { unsigned short us[4]; unsigned long long q; } o;
        #pragma unroll
        for (int i = 0; i < 4; ++i) o.us[i] = f2bf(acc[t2][mt][nt][i]);
        *(unsigned long long*)(gbase + roff + nt * 16 + kb * 4) = o.q;
      }
    }
  }
}

// Persistent bidirectional LSTM layer scan (R10/R13-proven, unchanged).
// Grid: 64 blocks x 256 threads; blocks 0..31 fwd, 32..63 bwd; 16 units/block.
// Whh slice in LDS (MFMA fragment order). h ping-pong through the coherent
// point (agent-scope); c in registers. Replicated flags; wave0 = h publish +
// flag (critical path), wave1 = act_out stores; lsm double-buffered.
// Floor analysis: ~5.5us/step = LLC round-trip chain (publish-ack -> flag ->
// poll-detect -> 64-block parallel h loads). Six protocol variants and two
// tilings bracket this floor; 64 blocks/dir maximizes load-stream parallelism.
template<int DIN, int GXP>
__global__ __launch_bounds__(256, 1)
void scan_kernel(const unsigned short* __restrict__ act_in,
                 const unsigned short* __restrict__ gates,   // [T][4096][64] bf16
                 unsigned short* __restrict__ act_out,
                 const unsigned short* __restrict__ wih_f,
                 const unsigned short* __restrict__ wih_b,
                 const unsigned short* __restrict__ whh_f,
                 const unsigned short* __restrict__ whh_b,
                 const float* __restrict__ bias_f,
                 const float* __restrict__ bias_b,
                 const float* __restrict__ init_f,
                 const float* __restrict__ init_b,
                 const float* __restrict__ masks,
                 unsigned short* hb,          // [2 dirs][2 slots][HSLOT] bf16
                 unsigned int* bar,           // per layer: 64 lines x 32 uints
                 float* out_h, float* out_c)
{
  const int bid  = blockIdx.x;
  const int dir  = bid >> 5;
  const int jb   = bid & (NBLK - 1);
  const int j0   = jb * UB;
  const int lane = threadIdx.x & 63;
  const int wave = threadIdx.x >> 6;
  const int n    = lane & 15;
  const int kb   = lane >> 4;
  const int u    = n & 7;
  const bool hif = (n >= 8);

  const unsigned short* wih = dir ? wih_b : wih_f;
  const unsigned short* whh = dir ? whh_b : whh_f;
  const float* bias = dir ? bias_b : bias_f;
  const float* init = dir ? init_b : init_f;
  const unsigned int* mypoll = bar + ((dir * 32 + jb) << 5) + (lane & 31);
  unsigned int* scat = bar + ((dir * 32 + (lane & 31)) << 5) + jb;  // lane<32
  unsigned short* hbd = hb + dir * (2 * HSLOT);
  float* oh = out_h + dir * (NBATCH * HID);
  float* oc = out_c + dir * (NBATCH * HID);

  int wr[4];
  wr[0] = hif ? (512 + j0 + u) : (j0 + u);
  wr[1] = wr[0] + 8;
  wr[2] = wr[0] + 1024;
  wr[3] = wr[0] + 1032;

  float bb[4];
  const unsigned short* wihp[4];
  #pragma unroll
  for (int q = 0; q < 4; ++q) {
    bb[q] = bias[wr[q]];
    wihp[q] = wih + (size_t)wr[q] * DIN + kb * 8;
  }

  __shared__ short8 wlds[16 * 4 * 64];               // 64 KB
  __shared__ unsigned short lsm[2][NBATCH * UB];     // 2x2 KB pack buffers

  for (int g = threadIdx.x; g < 4096; g += 256) {
    int n_ = g & 15, kb_ = (g >> 4) & 3, q_ = (g >> 6) & 3, ks_ = g >> 8;
    int grow = ((n_ >= 8) ? 512 : 0) + j0 + (n_ & 7) + (q_ & 1) * 8 + (q_ >> 1) * 1024;
    wlds[g] = *(const short8*)(whh + (size_t)grow * HID + ks_ * 32 + kb_ * 8);
  }

  float cs[2][4];
  #pragma unroll
  for (int uh = 0; uh < 2; ++uh)
    #pragma unroll
    for (int i = 0; i < 4; ++i)
      cs[uh][i] = init[512 + j0 + uh * 8 + u];

  __syncthreads();

  if (wave == 0) {
    union { unsigned short us[16]; unsigned long long q[4]; } iv;
    #pragma unroll
    for (int k = 0; k < 16; ++k) iv.us[k] = f2bf(init[j0 + k]);
    unsigned long long* hd = (unsigned long long*)(hbd + jb * (NBATCH * UB) + lane * UB);
    #pragma unroll
    for (int k = 0; k < 4; ++k) st_u64(hd + k, iv.q[k]);
    asm volatile("s_waitcnt vmcnt(0)" ::: "memory");
    if (lane < 32) st_flag(scat, 1u);
  }

  f32x4 acc_e[4], acc_o[4];

  auto wih_load = [&](int tstep) {
    #pragma unroll
    for (int q = 0; q < 4; ++q) {
      acc_e[q] = (f32x4){bb[q], bb[q], bb[q], bb[q]};
      acc_o[q] = (f32x4){0.f, 0.f, 0.f, 0.f};
    }
    const int tt2 = dir ? (TSTEPS - 1 - tstep) : tstep;
    const unsigned short* arow = act_in + ((size_t)tt2 * NBATCH + wave * 16 + n) * DIN + kb * 8;
    #pragma unroll
    for (int kt = 0; kt < DIN / 32; kt += 2) {
      short8 a0 = *(const short8*)(arow + kt * 32);
      short8 a1 = *(const short8*)(arow + kt * 32 + 32);
      #pragma unroll
      for (int q = 0; q < 4; ++q) {
        acc_e[q] = MFMA_B16(a0, *(const short8*)(wihp[q] + kt * 32), acc_e[q]);
        acc_o[q] = MFMA_B16(a1, *(const short8*)(wihp[q] + kt * 32 + 32), acc_o[q]);
      }
    }
  };

  if (!GXP) wih_load(0);

  for (int t = 0; t < TSTEPS; ++t) {
    const int tt = dir ? (TSTEPS - 1 - t) : t;

    // prefetch: mask + gate pre-activations, issued before the poll
    f32x4 mk = *(const f32x4*)(masks + tt * NBATCH + wave * 16 + kb * 4);
    if (GXP) {
      const unsigned short* gb = gates + ((size_t)tt * 4096 + dir * 2048) * 64 + wave * 16 + kb * 4;
      #pragma unroll
      for (int q = 0; q < 4; ++q) {
        union { unsigned long long q8; unsigned short us[4]; } gv;
        gv.q8 = *(const unsigned long long*)(gb + (size_t)wr[q] * 64);
        acc_e[q] = (f32x4){bf2f(gv.us[0]), bf2f(gv.us[1]), bf2f(gv.us[2]), bf2f(gv.us[3])};
        acc_o[q] = (f32x4){0.f, 0.f, 0.f, 0.f};
      }
    }

    // wait for h(t-1): all waves poll this block's private flag line
    {
      const unsigned int tgt = t + 1;
      while (!__all((int)(ld_flag(mypoll) >= tgt)))
        __builtin_amdgcn_s_sleep(1);
    }

    // recurrent part: h(t-1) @ Whh_slice; h from coherent point, Whh from LDS
    {
      const unsigned short* hrow = hbd + (t & 1) * HSLOT
                                 + (kb >> 1) * 1024 + (kb & 1) * 8 + (wave * 16 + n) * UB;
      short8 hf[16];
      #pragma unroll
      for (int ks = 0; ks < 16; ++ks) hf[ks] = ld_llc16(hrow + ks * 2048);
      #pragma unroll
      for (int ks = 0; ks < 16; ++ks) {
        f32x4* ac = (ks & 1) ? acc_o : acc_e;
        #pragma unroll
        for (int q = 0; q < 4; ++q)
          ac[q] = MFMA_B16(hf[ks], wlds[(ks * 4 + q) * 64 + lane], ac[q]);
      }
    }

    #pragma unroll
    for (int uh = 0; uh < 2; ++uh) {
      f32x4 aif = acc_e[uh] + acc_o[uh];
      f32x4 ago = acc_e[2 + uh] + acc_o[2 + uh];
      f32x4 oif, ogo;
      #pragma unroll
      for (int r = 0; r < 4; ++r) {
        oif[r] = __shfl_xor(aif[r], 8, 64);
        ogo[r] = __shfl_xor(ago[r], 8, 64);
      }
      #pragma unroll
      for (int i = 0; i < 4; ++i) {
        float vi = hif ? oif[i] : aif[i];
        float vf = hif ? aif[i] : oif[i];
        float vg = hif ? ogo[i] : ago[i];
        float vo = hif ? ago[i] : ogo[i];
        float cn = (sigm(vf) * cs[uh][i] + sigm(vi) * tanhf_(vg)) * mk[i];
        float hvv = sigm(vo) * tanhf_(cn) * mk[i];
        cs[uh][i] = cn;
        if (!hif) {
          const int b = wave * 16 + kb * 4 + i;
          lsm[t & 1][b * UB + uh * 8 + u] = f2bf(hvv);
          if (t == TSTEPS - 1) {
            oh[b * HID + j0 + uh * 8 + u] = hvv;
            oc[b * HID + j0 + uh * 8 + u] = cn;
          }
        }
      }
    }

    __syncthreads();  // lsm[t&1] writes -> wave0/wave1 reads

    if (wave == 0) {
      // critical path: h publish + flag scatter only
      if (t + 1 < TSTEPS) {
        const unsigned long long* lq = (const unsigned long long*)lsm[t & 1];
        unsigned long long q0 = lq[lane * 4 + 0];
        unsigned long long q1 = lq[lane * 4 + 1];
        unsigned long long q2 = lq[lane * 4 + 2];
        unsigned long long q3 = lq[lane * 4 + 3];
        unsigned long long* hd = (unsigned long long*)
            (hbd + ((t + 1) & 1) * HSLOT + jb * (NBATCH * UB) + lane * UB);
        st_u64(hd + 0, q0); st_u64(hd + 1, q1);
        st_u64(hd + 2, q2); st_u64(hd + 3, q3);
        asm volatile("s_waitcnt vmcnt(0)" ::: "memory");
        if (lane < 32) st_flag(scat, (unsigned int)(t + 2));
      }
    } else if (wave == 1) {
      // act_out store, off the critical path; no vmcnt needed
      const unsigned long long* lq = (const unsigned long long*)lsm[t & 1];
      union { unsigned long long q[2]; short8 s; } p0, p1;
      p0.q[0] = lq[lane * 4 + 0]; p0.q[1] = lq[lane * 4 + 1];
      p1.q[0] = lq[lane * 4 + 2]; p1.q[1] = lq[lane * 4 + 3];
      short8* ar = (short8*)(act_out + ((size_t)tt * NBATCH + lane) * (2 * HID) + dir * HID + j0);
      ar[0] = p0.s;
      ar[1] = p1.s;
    }

    if (!GXP && t + 1 < TSTEPS) wih_load(t + 1);
  }
}

// Highway gate: g = sigmoid(raw @ projW^T + projb); out = g*raw + (1-g)*inp
template<int FINAL>
__global__ __launch_bounds__(256)
void highway_kernel(const unsigned short* __restrict__ raw,
                    unsigned short* __restrict__ inp,
                    const unsigned short* __restrict__ pw,
                    const float* __restrict__ pb,
                    float* __restrict__ outf)
{
  const int lane = threadIdx.x & 63;
  const int wave = threadIdx.x >> 6;
  const int n = lane & 15, kb = lane >> 4;
  const int r0 = blockIdx.x * 64 + wave * 16;
  const int c0 = blockIdx.y * 64;
  f32x4 acc[4];
  #pragma unroll
  for (int nt = 0; nt < 4; ++nt) {
    float b = pb[c0 + nt * 16 + n];
    acc[nt] = (f32x4){b, b, b, b};
  }
  const unsigned short* arow = raw + (r0 + n) * 1024 + kb * 8;
  #pragma unroll 4
  for (int kt = 0; kt < 32; ++kt) {
    short8 a = *(const short8*)(arow + kt * 32);
    #pragma unroll
    for (int nt = 0; nt < 4; ++nt) {
      short8 b = *(const short8*)(pw + (c0 + nt * 16 + n) * 1024 + kt * 32 + kb * 8);
      acc[nt] = MFMA_B16(a, b, acc[nt]);
    }
  }
  #pragma unroll
  for (int nt = 0; nt < 4; ++nt)
    #pragma unroll
    for (int i = 0; i < 4; ++i) {
      int row = r0 + kb * 4 + i;
      int col = c0 + nt * 16 + n;
      float g = sigm(acc[nt][i]);
      float rv = bf2f(raw[row * 1024 + col]);
      float iv = bf2f(inp[row * 1024 + col]);
      float ov = g * rv + (1.0f - g) * iv;
      if (FINAL) outf[row * 1024 + col] = ov;
      else       inp[row * 1024 + col] = f2bf(ov);
    }
}

extern "C" void kernel_launch(void* const* d_in, const int* in_sizes, int n_in,
                              void* d_out, int out_size, void* d_ws, size_t ws_size,
                              hipStream_t stream) {
  const float* x     = (const float*)d_in[0];
  const float* masks = (const float*)d_in[1];
  const float* fWih0 = (const float*)d_in[2];
  const float* fWihR = (const float*)d_in[3];
  const float* fWhh  = (const float*)d_in[4];
  const float* fb    = (const float*)d_in[5];
  const float* bWih0 = (const float*)d_in[6];
  const float* bWihR = (const float*)d_in[7];
  const float* bWhh  = (const float*)d_in[8];
  const float* bbias = (const float*)d_in[9];
  const float* fInit = (const float*)d_in[10];
  const float* bInit = (const float*)d_in[11];
  const float* projW = (const float*)d_in[12];
  const float* projB = (const float*)d_in[13];
  float* out = (float*)d_out;

  char* ws = (char*)d_ws;
  unsigned short* bufA  = (unsigned short*)(ws + 0);           // 33,554,432
  unsigned short* bufB  = (unsigned short*)(ws + 33554432);    // 33,554,432
  unsigned short* xbf   = (unsigned short*)(ws + 67108864);    // 16,777,216
  unsigned short* wcat0 = (unsigned short*)(ws + 83886080);    //  4,194,304
  unsigned short* wcat1 = (unsigned short*)(ws + 88080384);    //  8,388,608
  unsigned short* wcat2 = (unsigned short*)(ws + 96468992);    //  8,388,608
  unsigned short* whf   = (unsigned short*)(ws + 104857600);   //  6,291,456
  unsigned short* whb   = (unsigned short*)(ws + 111149056);   //  6,291,456
  unsigned short* pj    = (unsigned short*)(ws + 117440512);   //  4,194,304
  unsigned short* hbuf  = (unsigned short*)(ws + 121634816);   //    262,144
  unsigned int*   bar   = (unsigned int*)(ws + 121896960);     //     24,576
  unsigned short* gates = (unsigned short*)(ws + 121921536);   // 134,217,728
  const bool gx = ws_size >= 256139264ull;

  hipMemsetAsync(bar, 0, 24576, stream);
  cvt_all<<<1024, 256, 0, stream>>>(x, fWih0, bWih0, fWihR, bWihR, fWhh, bWhh, projW, xbf);

  float* outH = out + 16777216;
  float* outC = out + 16777216 + 6*64*512;

  if (gx) {
    // layer 0
    gates_gemm<512><<<dim3(128, 16), 256, 0, stream>>>(xbf, wcat0, fb, bbias, gates);
    scan_kernel<512, 1><<<64, 256, 0, stream>>>(
        xbf, gates, bufA,
        wcat0, wcat0 + 2048*512, whf, whb,
        fb, bbias, fInit, bInit, masks, hbuf, bar,
        outH, outC);
    // layer 1
    gates_gemm<1024><<<dim3(128, 16), 256, 0, stream>>>(bufA, wcat1, fb + 2048, bbias + 2048, gates);
    scan_kernel<1024, 1><<<64, 256, 0, stream>>>(
        bufA, gates, bufB,
        wcat1, wcat1 + 2048*1024, whf + 2048*512, whb + 2048*512,
        fb + 2048, bbias + 2048, fInit + 1024, bInit + 1024, masks, hbuf, bar + 2048,
        outH + 2*64*512, outC + 2*64*512);
    highway_kernel<0><<<dim3(256, 16), 256, 0, stream>>>(bufB, bufA, pj, projB, nullptr);
    // layer 2
    gates_gemm<1024><<<dim3(128, 16), 256, 0, stream>>>(bufA, wcat2, fb + 4096, bbias + 4096, gates);
    scan_kernel<1024, 1><<<64, 256, 0, stream>>>(
        bufA, gates, bufB,
        wcat2, wcat2 + 2048*1024, whf + 2*2048*512, whb + 2*2048*512,
        fb + 4096, bbias + 4096, fInit + 2048, bInit + 2048, masks, hbuf, bar + 4096,
        outH + 4*64*512, outC + 4*64*512);
    highway_kernel<1><<<dim3(256, 16), 256, 0, stream>>>(bufB, bufA, pj + 1024*1024, projB + 1024, out);
  } else {
    scan_kernel<512, 0><<<64, 256, 0, stream>>>(
        xbf, nullptr, bufA,
        wcat0, wcat0 + 2048*512, whf, whb,
        fb, bbias, fInit, bInit, masks, hbuf, bar,
        outH, outC);
    scan_kernel<1024, 0><<<64, 256, 0, stream>>>(
        bufA, nullptr, bufB,
        wcat1, wcat1 + 2048*1024, whf + 2048*512, whb + 2048*512,
        fb + 2048, bbias + 2048, fInit + 1024, bInit + 1024, masks, hbuf, bar + 2048,
        outH + 2*64*512, outC + 2*64*512);
    highway_kernel<0><<<dim3(256, 16), 256, 0, stream>>>(bufB, bufA, pj, projB, nullptr);
    scan_kernel<1024, 0><<<64, 256, 0, stream>>>(
        bufA, nullptr, bufB,
        wcat2, wcat2 + 2048*1024, whf + 2*2048*512, whb + 2*2048*512,
        fb + 4096, bbias + 4096, fInit + 2048, bInit + 2048, masks, hbuf, bar + 4096,
        outH + 4*64*512, outC + 4*64*512);
    highway_kernel<1><<<dim3(256, 16), 256, 0, stream>>>(bufB, bufA, pj + 1024*1024, projB + 1024, out);
  }
}